// Round 12
// baseline (1035.326 us; speedup 1.0000x reference)
//
#include <hip/hip_runtime.h>
#include <math.h>

#define BB 2
#define NN 100
#define TT 15
#define FF 6
#define KK 4
#define HH 128
#define EE 9900      // N*(N-1)
#define EPN 99       // edges per receiver (N-1)
#define NSTEP 14     // T-1
#define TILE_E 64
#define CHUNK 16     // W2 rows per pipeline chunk
#define NCHUNK 8     // 128 / 16

// fast transcendentals: v_exp_f32 + v_rcp_f32 based (~6 instr vs ~40 for libm)
__device__ __forceinline__ float fast_tanh(float x) {
    float e = __expf(2.0f * x);
    return 1.0f - __fdividef(2.0f, 1.0f + e);
}
__device__ __forceinline__ float fast_sig(float x) {
    return __fdividef(1.0f, 1.0f + __expf(-x));
}

// async global->LDS 16B copy (dest must be linear: wave-uniform base + lane*16)
__device__ __forceinline__ void load_lds16(const float4* g, float4* l) {
    __builtin_amdgcn_global_load_lds(
        (const __attribute__((address_space(1))) void*)g,
        (__attribute__((address_space(3))) void*)l, 16, 0, 0);
}

// ---------------------------------------------------------------------------
// K0: one-time init. hidden=0, agg4=0, Hs = 0, Hr = b1.
// ---------------------------------------------------------------------------
__global__ __launch_bounds__(256) void k_init(
    const float* __restrict__ b1,   // [K,H]
    float* __restrict__ hidden,     // [B,N,H]
    float* __restrict__ agg4,       // [K,B,N,H]
    float* __restrict__ Hs,         // [B,N,K,H]
    float* __restrict__ Hr)         // [B,N,K,H]
{
    int i = blockIdx.x * 256 + threadIdx.x;      // < 102400
    if (i < BB * NN * HH) hidden[i] = 0.f;
    agg4[i] = 0.f;
    int k  = (i >> 7) & 3;
    int hh = i & 127;
    Hs[i] = 0.f;
    Hr[i] = b1[k * HH + hh];
}

// ---------------------------------------------------------------------------
// K2 v5: edge messages for ONE edge type k (blockIdx.z), tile of 64 edges.
//   m1 in LDS (linear [64][128]); W2[k] pipelined through LDS in 16-row
//   chunks, double-buffered, staged via global_load_lds issued one chunk
//   ahead (prefetch overlaps GEMM; barrier's vmcnt drain lands it).
//   Register blocking 4 edges x 8 h; h-cols {hg*4..+3} u {64+hg*4..+3}
//   (2-way bank access = free, r10-verified conflict-free).
// grid: (155, B, K), 256 threads
// ---------------------------------------------------------------------------
__global__ __launch_bounds__(256) void k_edge(
    const float* __restrict__ Hs,        // [B,N,K,H]
    const float* __restrict__ Hr,        // [B,N,K,H]
    const float* __restrict__ W2,        // [K,H,H]
    const float* __restrict__ b2,        // [K,H]
    const float* __restrict__ rel_type,  // [B,E,K]
    float* __restrict__ agg4)            // [K,B,N,H] atomic accum
{
    const int tile = blockIdx.x;
    const int b    = blockIdx.y;
    const int k    = blockIdx.z;
    const int e0   = tile * TILE_E;
    const int t    = threadIdx.x;
    const int hg   = t & 15;        // 16 h-groups
    const int eg   = t >> 4;        // 16 edge-groups, 4 edges each (stride 16)
    const int cA   = hg * 4;        // first 4-col group
    const int cB   = 64 + hg * 4;   // second 4-col group

    __shared__ __align__(16) float m1s[TILE_E * HH];      // 32 KB, linear
    __shared__ __align__(16) float w2c[2][CHUNK * HH];    // 2 x 8 KB chunks
    __shared__ int s_send[TILE_E], s_recv[TILE_E];

    if (t < TILE_E) {
        int e = e0 + t;
        if (e >= EE) e = EE - 1;
        int r = e / EPN;
        int j = e - r * EPN;
        s_recv[t] = r;
        s_send[t] = j + (j >= r ? 1 : 0);
    }
    __syncthreads();

    const float4* W2f4 = (const float4*)(W2 + k * HH * HH);

    // ---- prefetch W2 chunk 0 (lands during m1 build; barrier drains it) ----
    load_lds16(W2f4 + t,       (float4*)w2c[0] + t);
    load_lds16(W2f4 + 256 + t, (float4*)w2c[0] + 256 + t);

    // ---- build m1 tile: 64 edges x 128, via float4 (2048 slots, 8/thread) ----
    const float4* Hs4 = (const float4*)Hs;
    const float4* Hr4 = (const float4*)Hr;
#pragma unroll
    for (int rep = 0; rep < 8; ++rep) {
        int idx = rep * 256 + t;
        int el  = idx >> 5;
        int f4  = idx & 31;
        int s   = s_send[el];
        int r   = s_recv[el];
        float4 a = Hs4[((b * NN + s) * KK + k) * 32 + f4];
        float4 c = Hr4[((b * NN + r) * KK + k) * 32 + f4];
        float4 v;
        v.x = fast_tanh(a.x + c.x);
        v.y = fast_tanh(a.y + c.y);
        v.z = fast_tanh(a.z + c.z);
        v.w = fast_tanh(a.w + c.w);
        *(float4*)&m1s[el * HH + f4 * 4] = v;
    }

    // ---- this thread's 4 edges (strided by 16) ----
    int   el[4], erecv[4];
    float relw[4];
    const float scale = 1.0f / (KK * FF);
#pragma unroll
    for (int ei = 0; ei < 4; ++ei) {
        int l = eg + 16 * ei;
        el[ei] = l;
        int e = e0 + l;
        bool valid = (e < EE);
        if (!valid) e = EE - 1;
        erecv[ei] = s_recv[l];
        relw[ei]  = valid ? rel_type[(b * EE + e) * KK + k] * scale : 0.f;
    }

    __syncthreads();   // m1 written, chunk 0 landed (implicit vmcnt/lgkm drain)

    // ---- GEMM: acc[4][8] over 128 j; 8 chunks, prefetch depth 1 ----
    const float4* m1f4 = (const float4*)m1s;
    float acc[4][8] = {};
    for (int c = 0; c < NCHUNK; ++c) {
        // prefetch next chunk into the idle buffer (reads of it finished
        // at the barrier ending iteration c-1)
        if (c + 1 < NCHUNK) {
            float4* nb = (float4*)w2c[(c + 1) & 1];
            load_lds16(W2f4 + (c + 1) * 512 + t,       nb + t);
            load_lds16(W2f4 + (c + 1) * 512 + 256 + t, nb + 256 + t);
        }
        const float4* wf = (const float4*)w2c[c & 1];
#pragma unroll
        for (int js = 0; js < 4; ++js) {     // j-quad within chunk
            float4 wA[4], wB[4];
#pragma unroll
            for (int jj = 0; jj < 4; ++jj) {
                wA[jj] = wf[(js * 4 + jj) * 32 + hg];
                wB[jj] = wf[(js * 4 + jj) * 32 + 16 + hg];
            }
#pragma unroll
            for (int ei = 0; ei < 4; ++ei) {
                float4 mv = m1f4[el[ei] * 32 + c * 4 + js];
                float* A = acc[ei];
                A[0] = fmaf(mv.x, wA[0].x, fmaf(mv.y, wA[1].x, fmaf(mv.z, wA[2].x, fmaf(mv.w, wA[3].x, A[0]))));
                A[1] = fmaf(mv.x, wA[0].y, fmaf(mv.y, wA[1].y, fmaf(mv.z, wA[2].y, fmaf(mv.w, wA[3].y, A[1]))));
                A[2] = fmaf(mv.x, wA[0].z, fmaf(mv.y, wA[1].z, fmaf(mv.z, wA[2].z, fmaf(mv.w, wA[3].z, A[2]))));
                A[3] = fmaf(mv.x, wA[0].w, fmaf(mv.y, wA[1].w, fmaf(mv.z, wA[2].w, fmaf(mv.w, wA[3].w, A[3]))));
                A[4] = fmaf(mv.x, wB[0].x, fmaf(mv.y, wB[1].x, fmaf(mv.z, wB[2].x, fmaf(mv.w, wB[3].x, A[4]))));
                A[5] = fmaf(mv.x, wB[0].y, fmaf(mv.y, wB[1].y, fmaf(mv.z, wB[2].y, fmaf(mv.w, wB[3].y, A[5]))));
                A[6] = fmaf(mv.x, wB[0].z, fmaf(mv.y, wB[1].z, fmaf(mv.z, wB[2].z, fmaf(mv.w, wB[3].z, A[6]))));
                A[7] = fmaf(mv.x, wB[0].w, fmaf(mv.y, wB[1].w, fmaf(mv.z, wB[2].w, fmaf(mv.w, wB[3].w, A[7]))));
            }
        }
        __syncthreads();   // reads of chunk c done; prefetch c+1 landed
    }

    // ---- epilogue: m2 = tanh(acc + b2), weight, bin by receiver (<=2/tile) ----
    float b2k[8];
    *(float4*)&b2k[0] = *(const float4*)&b2[k * HH + cA];
    *(float4*)&b2k[4] = *(const float4*)&b2[k * HH + cB];

    const int rA = s_recv[0];
    const int rB = s_recv[TILE_E - 1];
    float sumA[8] = {}, sumB[8] = {};
#pragma unroll
    for (int ei = 0; ei < 4; ++ei) {
        bool isA = (erecv[ei] == rA);
#pragma unroll
        for (int h = 0; h < 8; ++h) {
            float v = relw[ei] * fast_tanh(acc[ei][h] + b2k[h]);
            if (isA) sumA[h] += v; else sumB[h] += v;
        }
    }

    float* red  = m1s;   // reuse as [16][128]
    float* aggk = agg4 + ((size_t)(k * BB + b)) * NN * HH;
    // last loop iteration ended with __syncthreads(): m1 reads complete
    *(float4*)&red[eg * 128 + cA] = make_float4(sumA[0], sumA[1], sumA[2], sumA[3]);
    *(float4*)&red[eg * 128 + cB] = make_float4(sumA[4], sumA[5], sumA[6], sumA[7]);
    __syncthreads();
    if (t < HH) {
        float s = 0.f;
#pragma unroll
        for (int y = 0; y < 16; ++y) s += red[y * 128 + t];
        atomicAdd(&aggk[rA * HH + t], s);
    }
    if (rB != rA) {            // block-uniform
        __syncthreads();       // pass-A reads done
        *(float4*)&red[eg * 128 + cA] = make_float4(sumB[0], sumB[1], sumB[2], sumB[3]);
        *(float4*)&red[eg * 128 + cB] = make_float4(sumB[4], sumB[5], sumB[6], sumB[7]);
        __syncthreads();
        if (t < HH) {
            float s = 0.f;
#pragma unroll
            for (int y = 0; y < 16; ++y) s += red[y * 128 + t];
            atomicAdd(&aggk[rB * HH + t], s);
        }
    }
}

// ---------------------------------------------------------------------------
// K3 v2: GRU + output MLP + next-step projections. 512 threads (8 waves):
// j-chains split 4-way (gates/MLP, chain 32) and 4-plane x 2-half (proj,
// chain 64); partials reduced through LDS.
// grid: B*N blocks
// ---------------------------------------------------------------------------
__global__ __launch_bounds__(512) void k_gru_out(
    const float* __restrict__ data,   // [B,N,T,F]
    float* __restrict__ agg4,         // [K,B,N,H] read then zeroed
    float* __restrict__ hidden,       // [B,N,H]
    const float* __restrict__ W1,  const float* __restrict__ b1,
    const float* __restrict__ Whr, const float* __restrict__ Whi,
    const float* __restrict__ Whh,
    const float* __restrict__ Wir, const float* __restrict__ bir,
    const float* __restrict__ Wii, const float* __restrict__ bii,
    const float* __restrict__ Win, const float* __restrict__ bin_,
    const float* __restrict__ Wo1, const float* __restrict__ bo1,
    const float* __restrict__ Wo2, const float* __restrict__ bo2,
    const float* __restrict__ Wo3, const float* __restrict__ bo3,
    float* __restrict__ Hs,           // [B,N,K,H]
    float* __restrict__ Hr,           // [B,N,K,H]
    float* __restrict__ out,          // [B,N,NSTEP,F]
    const int* __restrict__ ps_ptr, int step)
{
    const int bn = blockIdx.x;
    const int t  = threadIdx.x;   // 0..511
    const int tt = t & 127;       // output column
    const int q  = t >> 7;        // 0..3 j-quarter / task group

    __shared__ float sa[HH], sh[HH], p1b[HH], p2b[HH], insb[8];
    __shared__ float ap[4][HH];      // agg partials (per k)
    __shared__ float gp[3][4][HH];   // gate partials
    __shared__ float mp[4][HH];      // mlp partials
    __shared__ float pp[16][HH];     // proj partials (plane*2+half)

    {   // agg read + zero: one element per thread (k=q, col=tt)
        size_t idx = ((size_t)q * BB * NN + bn) * HH + tt;
        ap[q][tt] = agg4[idx];
        agg4[idx] = 0.f;
    }
    if (t < FF) {
        int ps = ps_ptr[0];
        bool use_gt = (ps <= 1) || (step % ps == 0);
        int prev = (step > 0) ? (step - 1) : 0;
        float gt = data[(bn * TT + step) * FF + t];
        float pv = out[(bn * NSTEP + prev) * FF + t];
        insb[t] = use_gt ? gt : pv;
    }
    __syncthreads();
    if (t < HH) sa[t] = ap[0][t] + ap[1][t] + ap[2][t] + ap[3][t];
    __syncthreads();

    {   // gate GEMV partials: 3 gates, chain 32
        const int j0 = q * 32;
        float pr = 0.f, pi = 0.f, ph = 0.f;
#pragma unroll 8
        for (int jj = 0; jj < 32; ++jj) {
            int j = j0 + jj;
            float a = sa[j];
            pr = fmaf(a, Whr[j * HH + tt], pr);
            pi = fmaf(a, Whi[j * HH + tt], pi);
            ph = fmaf(a, Whh[j * HH + tt], ph);
        }
        gp[0][q][tt] = pr; gp[1][q][tt] = pi; gp[2][q][tt] = ph;
    }
    __syncthreads();

    if (t < HH) {
        float ar = gp[0][0][t] + gp[0][1][t] + gp[0][2][t] + gp[0][3][t];
        float ai = gp[1][0][t] + gp[1][1][t] + gp[1][2][t] + gp[1][3][t];
        float ah = gp[2][0][t] + gp[2][1][t] + gp[2][2][t] + gp[2][3][t];
        float xr = bir[t], xi = bii[t], xn = bin_[t];
#pragma unroll
        for (int f = 0; f < FF; ++f) {
            float v = insb[f];
            xr = fmaf(v, Wir[f * HH + t], xr);
            xi = fmaf(v, Wii[f * HH + t], xi);
            xn = fmaf(v, Win[f * HH + t], xn);
        }
        float r  = fast_sig(xr + ar);
        float i  = fast_sig(xi + ai);
        float n  = fast_tanh(xn + r * ah);
        float hnew = (1.f - i) * n + i * hidden[bn * HH + t];
        hidden[bn * HH + t] = hnew;
        sh[t] = hnew;
    }
    __syncthreads();

    {   // MLP1 partial: chain 32
        const int j0 = q * 32;
        float a1 = 0.f;
#pragma unroll 8
        for (int jj = 0; jj < 32; ++jj) { int j = j0 + jj; a1 = fmaf(sh[j], Wo1[j * HH + tt], a1); }
        mp[q][tt] = a1;
    }
    __syncthreads();
    if (t < HH) p1b[t] = fmaxf(mp[0][t] + mp[1][t] + mp[2][t] + mp[3][t] + bo1[t], 0.f);
    __syncthreads();
    {   // MLP2 partial: chain 32
        const int j0 = q * 32;
        float a2 = 0.f;
#pragma unroll 8
        for (int jj = 0; jj < 32; ++jj) { int j = j0 + jj; a2 = fmaf(p1b[j], Wo2[j * HH + tt], a2); }
        mp[q][tt] = a2;
    }
    __syncthreads();
    if (t < HH) p2b[t] = fmaxf(mp[0][t] + mp[1][t] + mp[2][t] + mp[3][t] + bo2[t], 0.f);
    __syncthreads();

    if (t < FF) {
        float o = bo3[t];
#pragma unroll 4
        for (int j = 0; j < HH; ++j) o = fmaf(p2b[j], Wo3[j * FF + t], o);
        out[(bn * NSTEP + step) * FF + t] = insb[t] + o;
    }

    {   // next-step projections: 4 (plane,half) combos per thread, chain 64
#pragma unroll
        for (int i = 0; i < 4; ++i) {
            int c     = 4 * q + i;       // 0..15
            int plane = c >> 1;          // 0..7  (= 2k+which)
            int half  = c & 1;
            const float* Wp = W1 + (size_t)plane * HH * HH + tt;
            const int j0 = half * 64;
            float acc = 0.f;
#pragma unroll 8
            for (int jj = 0; jj < 64; ++jj) {
                int j = j0 + jj;
                acc = fmaf(sh[j], Wp[j * HH], acc);
            }
            pp[c][tt] = acc;
        }
    }
    __syncthreads();
    for (int o = t; o < 1024; o += 512) {
        int plane = o >> 7;          // 0..7
        int col   = o & 127;
        float v = pp[plane * 2][col] + pp[plane * 2 + 1][col];
        int kk = plane >> 1, which = plane & 1;
        if (which == 0) Hs[(bn * KK + kk) * HH + col] = v;
        else            Hr[(bn * KK + kk) * HH + col] = v + b1[kk * HH + col];
    }
}

// ---------------------------------------------------------------------------
extern "C" void kernel_launch(void* const* d_in, const int* in_sizes, int n_in,
                              void* d_out, int out_size, void* d_ws, size_t ws_size,
                              hipStream_t stream) {
    const float* data     = (const float*)d_in[0];
    const float* rel_type = (const float*)d_in[1];
    // d_in[2] rel_rec, d_in[3] rel_send: fixed off-diagonal structure, derived analytically
    const int*   ps_ptr   = (const int*)d_in[4];
    const float* W1   = (const float*)d_in[5];
    const float* b1   = (const float*)d_in[6];
    const float* W2   = (const float*)d_in[7];
    const float* b2   = (const float*)d_in[8];
    const float* Whr  = (const float*)d_in[9];
    const float* Whi  = (const float*)d_in[10];
    const float* Whh  = (const float*)d_in[11];
    const float* Wir  = (const float*)d_in[12];
    const float* bir  = (const float*)d_in[13];
    const float* Wii  = (const float*)d_in[14];
    const float* bii  = (const float*)d_in[15];
    const float* Win  = (const float*)d_in[16];
    const float* bin_ = (const float*)d_in[17];
    const float* Wo1  = (const float*)d_in[18];
    const float* bo1  = (const float*)d_in[19];
    const float* Wo2  = (const float*)d_in[20];
    const float* bo2  = (const float*)d_in[21];
    const float* Wo3  = (const float*)d_in[22];
    const float* bo3  = (const float*)d_in[23];

    float* out = (float*)d_out;

    float* ws     = (float*)d_ws;
    float* hidden = ws;                       // B*N*H      = 25600
    float* Hs     = ws + 25600;               // B*N*K*H    = 102400
    float* Hr     = ws + 128000;              // B*N*K*H    = 102400
    float* agg4   = ws + 230400;              // K*B*N*H    = 102400

    k_init<<<400, 256, 0, stream>>>(b1, hidden, agg4, Hs, Hr);

    const int ntile = (EE + TILE_E - 1) / TILE_E;   // 155
    dim3 egrid(ntile, BB, KK);

    for (int step = 0; step < NSTEP; ++step) {
        k_edge<<<egrid, 256, 0, stream>>>(Hs, Hr, W2, b2, rel_type, agg4);
        k_gru_out<<<BB * NN, 512, 0, stream>>>(data, agg4, hidden,
                                               W1, b1,
                                               Whr, Whi, Whh,
                                               Wir, bir, Wii, bii, Win, bin_,
                                               Wo1, bo1, Wo2, bo2, Wo3, bo3,
                                               Hs, Hr, out, ps_ptr, step);
    }
}